// Round 4
// baseline (124.740 us; speedup 1.0000x reference)
//
#include <hip/hip_runtime.h>
#include <hip/hip_cooperative_groups.h>

namespace cg = cooperative_groups;

#define NN 1024
#define EE 64
#define NPARTS 16

// ============================================================================
// Fused cooperative kernel: 256 blocks x 1024 threads (1 block/CU).
// P1 partials -> P2 base -> P3 serial scan (block 0) -> P4 epilogue
// ============================================================================
__global__ __launch_bounds__(1024) void s2v_fused(
    const float* __restrict__ nf, const float* __restrict__ cost,
    const float* __restrict__ W1, const float* __restrict__ b1,
    const float* __restrict__ W2, const float* __restrict__ b2,
    const float* __restrict__ w4, const float* __restrict__ b4,
    const float* __restrict__ W5, const float* __restrict__ b5,
    const float* __restrict__ W6, const float* __restrict__ b6,
    const float* __restrict__ W7, const float* __restrict__ b7,
    float* __restrict__ partial, float* __restrict__ base,
    float* __restrict__ v2o, float* __restrict__ Co,
    float* __restrict__ q)
{
    cg::grid_group grid = cg::this_grid();
    const int gid = blockIdx.x;
    const int tid = threadIdx.x;

    __shared__ float WL[64 * 65];   // W2 (P3, block 0) then W7 (P4, all)
    __shared__ float sP[1024];
    __shared__ float sS[64];
    __shared__ float sV[64];
    __shared__ float embL[4 * 64];

    // ---- P1: partial[jc][i][e] = sum_{j in chunk} relu(cost[j][i]*w4[e]+b4[e])
    {
        const int it = gid & 15;        // 16 i-tiles of 64
        const int jc = gid >> 4;        // 16 j-chunks of 64
        const int il = tid & 63;
        const int eg = tid >> 6;        // 16 e-groups of 4
        const int i  = it * 64 + il;

        float w4v[4], b4v[4];
#pragma unroll
        for (int ee = 0; ee < 4; ++ee) {
            w4v[ee] = w4[eg * 4 + ee];
            b4v[ee] = b4[eg * 4 + ee];
        }
        float a0 = 0.f, a1 = 0.f, a2 = 0.f, a3 = 0.f;
        const float* cp = cost + (size_t)jc * 64 * NN + i;
#pragma unroll 8
        for (int jj = 0; jj < 64; ++jj) {
            float cv = cp[(size_t)jj * NN];
            a0 += fmaxf(fmaf(cv, w4v[0], b4v[0]), 0.f);
            a1 += fmaxf(fmaf(cv, w4v[1], b4v[1]), 0.f);
            a2 += fmaxf(fmaf(cv, w4v[2], b4v[2]), 0.f);
            a3 += fmaxf(fmaf(cv, w4v[3], b4v[3]), 0.f);
        }
        float4 v = make_float4(a0, a1, a2, a3);
        *(float4*)(partial + ((size_t)jc * NN + i) * EE + eg * 4) = v;
    }
    grid.sync();

    // ---- P2: base[i][e] = x[i]*W1[e] + b1[e] + sum_p partial[p][i][e]
    if (tid < 256) {
        const int idx = gid * 256 + tid;   // 65536 total
        const int i = idx >> 6, e = idx & 63;
        float s = fmaf(nf[i], W1[e], b1[e]);
#pragma unroll
        for (int p = 0; p < NPARTS; ++p)
            s += partial[(size_t)p * (NN * EE) + idx];
        base[idx] = s;
    }
    grid.sync();

    // ---- P3: 4-step scan collapsed to E-vector recurrence (block 0 only)
    if (gid == 0) {
        const int c = tid & 63;
        const int g = tid >> 6;
#pragma unroll
        for (int m = tid; m < 4096; m += 1024)
            WL[(m >> 6) * 65 + (m & 63)] = W2[m];
        float bl[64];
#pragma unroll
        for (int rr = 0; rr < 64; ++rr)
            bl[rr] = base[(size_t)(g * 64 + rr) * EE + c];
        if (tid < 64) sS[c] = 0.f;
        __syncthreads();

        for (int t = 0; t < 4; ++t) {
            if (tid < 64) {
                float v = b2[c];
#pragma unroll
                for (int k = 0; k < 64; ++k) v = fmaf(WL[c * 65 + k], sS[k], v);
                sV[c] = v;
            }
            __syncthreads();
            float v2c = sV[c];
            float acc = 0.f;
#pragma unroll
            for (int rr = 0; rr < 64; ++rr) acc += fmaxf(bl[rr] + v2c, 0.f);
            sP[tid] = acc;
            __syncthreads();
            if (tid < 64) {
                float s = 0.f;
#pragma unroll
                for (int gg = 0; gg < 16; ++gg) s += sP[gg * 64 + c];
                sS[c] = s;
            }
            __syncthreads();
        }

        if (tid < 64) {
            float h = b6[c];
            for (int k = 0; k < 64; ++k) h = fmaf(W6[c * 64 + k], sS[k], h);
            float p = fmaxf(h, 0.f) * W5[c];
#pragma unroll
            for (int off = 32; off > 0; off >>= 1) p += __shfl_down(p, off, 64);
            v2o[c] = sV[c];
            if (tid == 0) Co[0] = p;
        }
    }
    grid.sync();

    // ---- P4: q[i] = b5 + C + sum_e relu(emb[i]@W7[e]+b7[e])*W5[E+e]
    {
#pragma unroll
        for (int m = tid; m < 4096; m += 1024)
            WL[(m >> 6) * 65 + (m & 63)] = W7[m];
        const int lane = tid & 63;
        const int w = tid >> 6;         // 16 waves; 4 active rows/block
        if (w < 4) {
            const int i = gid * 4 + w;
            embL[w * 64 + lane] =
                fmaxf(base[(size_t)i * EE + lane] + v2o[lane], 0.f);
        }
        __syncthreads();
        if (w < 4) {
            const int i = gid * 4 + w;
            float h = b7[lane];
#pragma unroll
            for (int k = 0; k < 64; ++k)
                h = fmaf(embL[w * 64 + k], WL[lane * 65 + k], h);
            float p = fmaxf(h, 0.f) * W5[64 + lane];
#pragma unroll
            for (int off = 32; off > 0; off >>= 1) p += __shfl_down(p, off, 64);
            if (lane == 0) q[i] = p + Co[0] + b5[0];
        }
    }
}

// ============================================================================
// Fallback path (proven R3 kernels) in case ws_size is too small
// ============================================================================
__global__ __launch_bounds__(256) void k1a_part(
    const float* __restrict__ cost,
    const float* __restrict__ w4, const float* __restrict__ b4,
    float* __restrict__ partial)
{
    const int it = blockIdx.x;
    const int jc = blockIdx.y;
    const int jspan = NN / gridDim.y;
    const int tid = threadIdx.x;
    const int il = tid & 31;
    const int eg = tid >> 5;
    const int i = it * 32 + il;
    const int j0 = jc * jspan;

    float w4v[8], b4v[8];
#pragma unroll
    for (int ee = 0; ee < 8; ++ee) {
        w4v[ee] = w4[eg * 8 + ee];
        b4v[ee] = b4[eg * 8 + ee];
    }
    float acc[8];
#pragma unroll
    for (int ee = 0; ee < 8; ++ee) acc[ee] = 0.f;

    const float* cp = cost + (size_t)j0 * NN + i;
#pragma unroll 8
    for (int jj = 0; jj < jspan; ++jj) {
        float cv = cp[(size_t)jj * NN];
#pragma unroll
        for (int ee = 0; ee < 8; ++ee)
            acc[ee] += fmaxf(fmaf(cv, w4v[ee], b4v[ee]), 0.f);
    }
    float* dst = partial + ((size_t)jc * NN + i) * EE + eg * 8;
    *(float4*)(dst)     = make_float4(acc[0], acc[1], acc[2], acc[3]);
    *(float4*)(dst + 4) = make_float4(acc[4], acc[5], acc[6], acc[7]);
}

__global__ __launch_bounds__(256) void k1b_reduce(
    const float* __restrict__ nf,
    const float* __restrict__ W1, const float* __restrict__ b1,
    const float* __restrict__ partial, int nparts,
    float* __restrict__ base)
{
    const int idx = blockIdx.x * 256 + threadIdx.x;
    const int i = idx >> 6;
    const int e = idx & 63;
    float s = fmaf(nf[i], W1[e], b1[e]);
    for (int p = 0; p < nparts; ++p)
        s += partial[(size_t)p * (NN * EE) + idx];
    base[idx] = s;
}

__global__ __launch_bounds__(1024) void k2_scan(
    const float* __restrict__ base,
    const float* __restrict__ W2, const float* __restrict__ b2,
    const float* __restrict__ W5,
    const float* __restrict__ W6, const float* __restrict__ b6,
    float* __restrict__ v2out, float* __restrict__ Cout)
{
    __shared__ float W2L[64 * 65];
    __shared__ float sP[1024];
    __shared__ float sS[64];
    __shared__ float sV[64];
    const int tid = threadIdx.x;
    const int c = tid & 63;
    const int g = tid >> 6;
#pragma unroll
    for (int m = tid; m < 4096; m += 1024)
        W2L[(m >> 6) * 65 + (m & 63)] = W2[m];
    float bl[64];
#pragma unroll
    for (int rr = 0; rr < 64; ++rr)
        bl[rr] = base[(size_t)(g * 64 + rr) * EE + c];
    if (tid < 64) sS[c] = 0.f;
    __syncthreads();
    for (int t = 0; t < 4; ++t) {
        if (tid < 64) {
            float v = b2[c];
#pragma unroll
            for (int k = 0; k < 64; ++k) v = fmaf(W2L[c * 65 + k], sS[k], v);
            sV[c] = v;
        }
        __syncthreads();
        float v2c = sV[c];
        float acc = 0.f;
#pragma unroll
        for (int rr = 0; rr < 64; ++rr) acc += fmaxf(bl[rr] + v2c, 0.f);
        sP[tid] = acc;
        __syncthreads();
        if (tid < 64) {
            float s = 0.f;
#pragma unroll
            for (int gg = 0; gg < 16; ++gg) s += sP[gg * 64 + c];
            sS[c] = s;
        }
        __syncthreads();
    }
    if (tid < 64) {
        float h = b6[c];
        for (int k = 0; k < 64; ++k) h = fmaf(W6[c * 64 + k], sS[k], h);
        float p = fmaxf(h, 0.f) * W5[c];
#pragma unroll
        for (int off = 32; off > 0; off >>= 1) p += __shfl_down(p, off, 64);
        v2out[c] = sV[c];
        if (tid == 0) Cout[0] = p;
    }
}

__global__ __launch_bounds__(256) void k3_out(
    const float* __restrict__ base,
    const float* __restrict__ W7, const float* __restrict__ b7,
    const float* __restrict__ W5, const float* __restrict__ b5,
    const float* __restrict__ v2, const float* __restrict__ Cin,
    float* __restrict__ q)
{
    __shared__ float W7L[64 * 65];
    __shared__ float embL[4 * 64];
    const int tid = threadIdx.x;
    const int lane = tid & 63;
    const int rl = tid >> 6;
    const int i = blockIdx.x * 4 + rl;
    for (int m = tid; m < 4096; m += 256)
        W7L[(m >> 6) * 65 + (m & 63)] = W7[m];
    float ev = fmaxf(base[(size_t)i * EE + lane] + v2[lane], 0.f);
    embL[rl * 64 + lane] = ev;
    __syncthreads();
    float h = b7[lane];
#pragma unroll
    for (int k = 0; k < 64; ++k)
        h = fmaf(embL[rl * 64 + k], W7L[lane * 65 + k], h);
    float p = fmaxf(h, 0.f) * W5[64 + lane];
#pragma unroll
    for (int off = 32; off > 0; off >>= 1) p += __shfl_down(p, off, 64);
    if (lane == 0) q[i] = p + Cin[0] + b5[0];
}

extern "C" void kernel_launch(void* const* d_in, const int* in_sizes, int n_in,
                              void* d_out, int out_size, void* d_ws, size_t ws_size,
                              hipStream_t stream)
{
    (void)in_sizes; (void)n_in; (void)out_size;
    const float* nf   = (const float*)d_in[0];
    const float* cost = (const float*)d_in[1];
    const float* W1   = (const float*)d_in[2];
    const float* b1   = (const float*)d_in[3];
    const float* W2   = (const float*)d_in[4];
    const float* b2   = (const float*)d_in[5];
    const float* w4   = (const float*)d_in[6];
    const float* b4   = (const float*)d_in[7];
    const float* W5   = (const float*)d_in[8];
    const float* b5   = (const float*)d_in[9];
    const float* W6   = (const float*)d_in[10];
    const float* b6   = (const float*)d_in[11];
    const float* W7   = (const float*)d_in[12];
    const float* b7   = (const float*)d_in[13];
    float* q = (float*)d_out;

    // ws layout: partial (NPARTS*NN*EE, 16B-aligned at offset 0), base, v2o, Co
    float* part = (float*)d_ws;
    float* base = part + (size_t)NPARTS * NN * EE;
    float* v2o  = base + (size_t)NN * EE;
    float* Co   = v2o + EE;

    size_t need = ((size_t)NPARTS * NN * EE + (size_t)NN * EE + EE + 1) * sizeof(float);

    if (ws_size >= need) {
        void* args[] = {
            (void*)&nf, (void*)&cost, (void*)&W1, (void*)&b1, (void*)&W2,
            (void*)&b2, (void*)&w4, (void*)&b4, (void*)&W5, (void*)&b5,
            (void*)&W6, (void*)&b6, (void*)&W7, (void*)&b7,
            (void*)&part, (void*)&base, (void*)&v2o, (void*)&Co, (void*)&q
        };
        hipLaunchCooperativeKernel((void*)s2v_fused, dim3(256), dim3(1024),
                                   args, 0, stream);
    } else {
        // fallback: 4-kernel chain with fewer partials
        float* fb_base = (float*)d_ws;
        float* fb_v2o  = fb_base + (size_t)NN * EE;
        float* fb_Co   = fb_v2o + EE;
        float* fb_part = fb_Co + 1;
        size_t fixed = ((size_t)NN * EE + EE + 1) * sizeof(float);
        size_t per_part = (size_t)NN * EE * sizeof(float);
        int nparts = 16;
        while (nparts > 1 && fixed + (size_t)nparts * per_part > ws_size) nparts >>= 1;
        dim3 g1(32, nparts);
        k1a_part<<<g1, 256, 0, stream>>>(cost, w4, b4, fb_part);
        k1b_reduce<<<256, 256, 0, stream>>>(nf, W1, b1, fb_part, nparts, fb_base);
        k2_scan<<<1, 1024, 0, stream>>>(fb_base, W2, b2, W5, W6, b6, fb_v2o, fb_Co);
        k3_out<<<256, 256, 0, stream>>>(fb_base, W7, b7, W5, b5, fb_v2o, fb_Co, q);
    }
}

// Round 5
// 32.470 us; speedup vs baseline: 3.8417x; 3.8417x over previous
//
#include <hip/hip_runtime.h>

#define NN 1024
#define EE 64

// K1a: partial[jc][i][e] = sum_{j in chunk} relu(cost[j][i]*w4[e] + b4[e])
// grid (32 i-tiles, nparts j-chunks), block 256 = 32 i-lanes x 8 e-groups(8 e)
__global__ __launch_bounds__(256) void k1a_part(
    const float* __restrict__ cost,
    const float* __restrict__ w4, const float* __restrict__ b4,
    float* __restrict__ partial)
{
    const int it = blockIdx.x;
    const int jc = blockIdx.y;
    const int jspan = NN / gridDim.y;
    const int tid = threadIdx.x;
    const int il = tid & 31;
    const int eg = tid >> 5;
    const int i = it * 32 + il;
    const int j0 = jc * jspan;

    float w4v[8], b4v[8];
#pragma unroll
    for (int ee = 0; ee < 8; ++ee) {
        w4v[ee] = w4[eg * 8 + ee];
        b4v[ee] = b4[eg * 8 + ee];
    }
    float acc[8];
#pragma unroll
    for (int ee = 0; ee < 8; ++ee) acc[ee] = 0.f;

    const float* cp = cost + (size_t)j0 * NN + i;
#pragma unroll 8
    for (int jj = 0; jj < jspan; ++jj) {
        float cv = cp[(size_t)jj * NN];
#pragma unroll
        for (int ee = 0; ee < 8; ++ee)
            acc[ee] += fmaxf(fmaf(cv, w4v[ee], b4v[ee]), 0.f);
    }
    float* dst = partial + ((size_t)jc * NN + i) * EE + eg * 8;
    *(float4*)(dst)     = make_float4(acc[0], acc[1], acc[2], acc[3]);
    *(float4*)(dst + 4) = make_float4(acc[4], acc[5], acc[6], acc[7]);
}

// K1b: base[i][e] = x[i]*W1[e] + b1[e] + sum_p partial[p][i][e]
__global__ __launch_bounds__(256) void k1b_reduce(
    const float* __restrict__ nf,
    const float* __restrict__ W1, const float* __restrict__ b1,
    const float* __restrict__ partial, int nparts,
    float* __restrict__ base)
{
    const int idx = blockIdx.x * 256 + threadIdx.x;
    const int i = idx >> 6;
    const int e = idx & 63;
    float s0 = fmaf(nf[i], W1[e], b1[e]);
    float s1 = 0.f;
#pragma unroll 4
    for (int p = 0; p + 1 < nparts; p += 2) {
        s0 += partial[(size_t)p * (NN * EE) + idx];
        s1 += partial[(size_t)(p + 1) * (NN * EE) + idx];
    }
    if (nparts & 1) s0 += partial[(size_t)(nparts - 1) * (NN * EE) + idx];
    base[idx] = s0 + s1;
}

// K23: fused scan + epilogue. 64 blocks x 1024 threads.
// Every block redundantly computes the 4-step scan (base is L2-resident),
// then its 16 waves each produce one output row (16 rows/block).
__global__ __launch_bounds__(1024) void k23_fused(
    const float* __restrict__ base,
    const float* __restrict__ W2, const float* __restrict__ b2,
    const float* __restrict__ W5, const float* __restrict__ b5,
    const float* __restrict__ W6, const float* __restrict__ b6,
    const float* __restrict__ W7, const float* __restrict__ b7,
    float* __restrict__ q)
{
    __shared__ float W2L[64 * 65];
    __shared__ float W7L[64 * 65];
    __shared__ float sP[1024];
    __shared__ float sS[64];
    __shared__ float sV[64];
    __shared__ float embL[16 * 64];
    __shared__ float sC;

    const int tid = threadIdx.x;
    const int c = tid & 63;     // column / e index within wave
    const int g = tid >> 6;     // wave id, 0..15

    // stage W2 and W7 with +1 padding (conflict-free matvec reads)
#pragma unroll
    for (int m = tid; m < 4096; m += 1024) {
        W2L[(m >> 6) * 65 + (m & 63)] = W2[m];
        W7L[(m >> 6) * 65 + (m & 63)] = W7[m];
    }

    // per-thread register cache of 64 base values (rows g*64..g*64+63, col c)
    float bl[64];
#pragma unroll
    for (int rr = 0; rr < 64; ++rr)
        bl[rr] = base[(size_t)(g * 64 + rr) * EE + c];

    if (tid < 64) sS[c] = 0.f;
    __syncthreads();

    // 4-step scan on the E-vector recurrence
    for (int t = 0; t < 4; ++t) {
        if (tid < 64) {
            float v = b2[c];
#pragma unroll
            for (int k = 0; k < 64; ++k) v = fmaf(W2L[c * 65 + k], sS[k], v);
            sV[c] = v;
        }
        __syncthreads();
        float v2c = sV[c];
        float a0 = 0.f, a1 = 0.f, a2 = 0.f, a3 = 0.f;
#pragma unroll
        for (int rr = 0; rr < 64; rr += 4) {
            a0 += fmaxf(bl[rr]     + v2c, 0.f);
            a1 += fmaxf(bl[rr + 1] + v2c, 0.f);
            a2 += fmaxf(bl[rr + 2] + v2c, 0.f);
            a3 += fmaxf(bl[rr + 3] + v2c, 0.f);
        }
        sP[tid] = (a0 + a1) + (a2 + a3);
        __syncthreads();
        if (tid < 64) {
            float s = 0.f;
#pragma unroll
            for (int gg = 0; gg < 16; ++gg) s += sP[gg * 64 + c];
            sS[c] = s;
        }
        __syncthreads();
    }
    // sV now holds v2_4; sS holds s_4.

    // C = sum_e relu(W6@s4 + b6)[e] * W5[0][e]  (wave 0)
    if (tid < 64) {
        float h = b6[c];
#pragma unroll
        for (int k = 0; k < 64; ++k) h = fmaf(W6[c * 64 + k], sS[k], h);
        float p = fmaxf(h, 0.f) * W5[c];
#pragma unroll
        for (int off = 32; off > 0; off >>= 1) p += __shfl_down(p, off, 64);
        if (tid == 0) sC = p;
    }

    // epilogue: wave g handles row i = blockIdx.x*16 + g
    const int i = blockIdx.x * 16 + g;
    embL[g * 64 + c] = fmaxf(base[(size_t)i * EE + c] + sV[c], 0.f);
    __syncthreads();

    float h = b7[c];
#pragma unroll
    for (int k = 0; k < 64; ++k)
        h = fmaf(embL[g * 64 + k], W7L[c * 65 + k], h);
    float p = fmaxf(h, 0.f) * W5[64 + c];
#pragma unroll
    for (int off = 32; off > 0; off >>= 1) p += __shfl_down(p, off, 64);
    if (c == 0) q[i] = p + sC + b5[0];
}

extern "C" void kernel_launch(void* const* d_in, const int* in_sizes, int n_in,
                              void* d_out, int out_size, void* d_ws, size_t ws_size,
                              hipStream_t stream)
{
    (void)in_sizes; (void)n_in; (void)out_size;
    const float* nf   = (const float*)d_in[0];
    const float* cost = (const float*)d_in[1];
    const float* W1   = (const float*)d_in[2];
    const float* b1   = (const float*)d_in[3];
    const float* W2   = (const float*)d_in[4];
    const float* b2   = (const float*)d_in[5];
    const float* w4   = (const float*)d_in[6];
    const float* b4   = (const float*)d_in[7];
    const float* W5   = (const float*)d_in[8];
    const float* b5   = (const float*)d_in[9];
    const float* W6   = (const float*)d_in[10];
    const float* b6   = (const float*)d_in[11];
    const float* W7   = (const float*)d_in[12];
    const float* b7   = (const float*)d_in[13];
    float* q = (float*)d_out;

    float* base = (float*)d_ws;              // NN*EE floats (16B aligned)
    float* part = base + (size_t)NN * EE;    // nparts * NN*EE floats

    size_t fixed = (size_t)NN * EE * sizeof(float);
    size_t per_part = (size_t)NN * EE * sizeof(float);
    int nparts = 16;
    while (nparts > 1 && fixed + (size_t)nparts * per_part > ws_size) nparts >>= 1;

    dim3 g1(32, nparts);
    k1a_part<<<g1, 256, 0, stream>>>(cost, w4, b4, part);
    k1b_reduce<<<256, 256, 0, stream>>>(nf, W1, b1, part, nparts, base);
    k23_fused<<<64, 1024, 0, stream>>>(base, W2, b2, W5, b5, W6, b6, W7, b7, q);
}